// Round 8
// baseline (301.483 us; speedup 1.0000x reference)
//
#include <hip/hip_runtime.h>
#include <cstdint>

// T=2048, D=1024, H=16, HS=64, DFF=4096. fp32 in/out, bf16 MFMA internally.

typedef __bf16 bf16;
typedef __bf16 bf16x4 __attribute__((ext_vector_type(4)));
typedef __bf16 bf16x8 __attribute__((ext_vector_type(8)));
typedef float floatx4 __attribute__((ext_vector_type(4)));

// async global->LDS 16B/lane. LDS dest is wave-uniform base + lane*16 (HW rule).
__device__ __forceinline__ void ld_g2l(const bf16* g, bf16* l) {
    __builtin_amdgcn_global_load_lds(
        (const __attribute__((address_space(1))) void*)g,
        (__attribute__((address_space(3))) void*)l, 16, 0, 0);
}

// ---------------------------------------------------------------------------
// Tiled transpose + fp32->bf16 cast:  dst[c][r] = (bf16)src[r][c], batched.
// ---------------------------------------------------------------------------
__global__ __launch_bounds__(256) void transpose_cast_kernel(
    const float* __restrict__ src, bf16* __restrict__ dst,
    int R, int C, long long sBatch, long long dBatch)
{
    __shared__ float tile[32][33];
    const int tx = threadIdx.x, ty = threadIdx.y;
    src += (size_t)blockIdx.z * sBatch;
    dst += (size_t)blockIdx.z * dBatch;
    const int c0 = blockIdx.x * 32, r0 = blockIdx.y * 32;
#pragma unroll
    for (int i = ty; i < 32; i += 8)
        tile[i][tx] = src[(size_t)(r0 + i) * C + c0 + tx];
    __syncthreads();
#pragma unroll
    for (int i = ty; i < 32; i += 8)
        dst[(size_t)(c0 + i) * R + r0 + tx] = (bf16)tile[tx][i];
}

// QKV weight transpose (3 sources in one launch): grid (2, 32, 48)
__global__ __launch_bounds__(256) void transpose_cast_qkv_kernel(
    const float* __restrict__ Wq, const float* __restrict__ Wk,
    const float* __restrict__ Wv, bf16* __restrict__ dst)
{
    __shared__ float tile[32][33];
    const int tx = threadIdx.x, ty = threadIdx.y;
    const int m = blockIdx.z >> 4, h = blockIdx.z & 15;
    const float* src = (m == 0 ? Wq : (m == 1 ? Wk : Wv)) + h * 65536;
    bf16* d = dst + m * 1048576 + h * 65536;
    const int c0 = blockIdx.x * 32, r0 = blockIdx.y * 32;
#pragma unroll
    for (int i = ty; i < 32; i += 8)
        tile[i][tx] = src[(size_t)(r0 + i) * 64 + c0 + tx];
    __syncthreads();
#pragma unroll
    for (int i = ty; i < 32; i += 8)
        d[(size_t)(c0 + i) * 1024 + r0 + tx] = (bf16)tile[tx][i];
}

// ---------------------------------------------------------------------------
// Head-transpose from QKV: dst[h][j][s] = qkv[s][colOff + h*64 + j]   (bf16)
// ---------------------------------------------------------------------------
__global__ __launch_bounds__(256) void transpose_head_kernel(
    const bf16* __restrict__ qkv, bf16* __restrict__ dst, int colOff)
{
    __shared__ bf16 tile[32][33];
    const int tx = threadIdx.x, ty = threadIdx.y;
    const int h = blockIdx.z;
    const int j0 = blockIdx.x * 32, s0 = blockIdx.y * 32;
#pragma unroll
    for (int i = ty; i < 32; i += 8)
        tile[i][tx] = qkv[(size_t)(s0 + i) * 3072 + colOff + h * 64 + j0 + tx];
    __syncthreads();
#pragma unroll
    for (int i = ty; i < 32; i += 8)
        dst[(size_t)h * 64 * 2048 + (size_t)(j0 + i) * 2048 + s0 + tx] = tile[tx][i];
}

// ---------------------------------------------------------------------------
// Row LayerNorm over D=1024: fp32 in -> bf16 out. One block (256 thr) per row.
// ---------------------------------------------------------------------------
__global__ __launch_bounds__(256) void ln_kernel(
    const float* __restrict__ x, const float* __restrict__ sc,
    const float* __restrict__ bi, bf16* __restrict__ out)
{
    const int row = blockIdx.x;
    const int tid = threadIdx.x;
    const float4 v = ((const float4*)(x + (size_t)row * 1024))[tid];
    float s1 = v.x + v.y + v.z + v.w;
    float s2 = v.x * v.x + v.y * v.y + v.z * v.z + v.w * v.w;
#pragma unroll
    for (int mm = 1; mm < 64; mm <<= 1) {
        s1 += __shfl_xor(s1, mm);
        s2 += __shfl_xor(s2, mm);
    }
    __shared__ float w1[4], w2[4];
    const int wave = tid >> 6, lane = tid & 63;
    if (lane == 0) { w1[wave] = s1; w2[wave] = s2; }
    __syncthreads();
    s1 = w1[0] + w1[1] + w1[2] + w1[3];
    s2 = w2[0] + w2[1] + w2[2] + w2[3];
    const float mu = s1 * (1.f / 1024.f);
    const float var = fmaxf(s2 * (1.f / 1024.f) - mu * mu, 0.f);
    const float rr = rsqrtf(var + 1e-6f);
    const float4 scv = ((const float4*)sc)[tid];
    const float4 biv = ((const float4*)bi)[tid];
    bf16x4 ov;
    ov[0] = (bf16)((v.x - mu) * rr * scv.x + biv.x);
    ov[1] = (bf16)((v.y - mu) * rr * scv.y + biv.y);
    ov[2] = (bf16)((v.z - mu) * rr * scv.z + biv.z);
    ov[3] = (bf16)((v.w - mu) * rr * scv.w + biv.w);
    *(bf16x4*)(out + (size_t)row * 1024 + tid * 4) = ov;
}

// ---------------------------------------------------------------------------
// Split-K reduce (4 partials):  out = p0+p1+p2+p3 + bias[col] + res
// ---------------------------------------------------------------------------
__global__ __launch_bounds__(256) void reduce4_kernel(
    const float* __restrict__ p, const float* __restrict__ bias,
    const float* __restrict__ res, float* __restrict__ out)
{
    const int idx = blockIdx.x * 256 + threadIdx.x;
    const int c4 = idx & 255;
    const float4 a0 = ((const float4*)p)[idx];
    const float4 a1 = ((const float4*)(p + 2097152))[idx];
    const float4 a2 = ((const float4*)(p + 4194304))[idx];
    const float4 a3 = ((const float4*)(p + 6291456))[idx];
    const float4 bi = ((const float4*)bias)[c4];
    const float4 r = ((const float4*)res)[idx];
    float4 o;
    o.x = (a0.x + a1.x) + (a2.x + a3.x) + bi.x + r.x;
    o.y = (a0.y + a1.y) + (a2.y + a3.y) + bi.y + r.y;
    o.z = (a0.z + a1.z) + (a2.z + a3.z) + bi.z + r.z;
    o.w = (a0.w + a1.w) + (a2.w + a3.w) + bi.w + r.w;
    ((float4*)out)[idx] = o;
}

// ---------------------------------------------------------------------------
// 128x128 MFMA GEMM (m97-class): BK=32, dbuf global_load_lds, bank swizzle,
// XCD swizzle <NG,MG>.
// MODE 0: outB=(bf16)acc | 2: outB=relu(acc+bias) | 3: psum[z*M*N+..]=acc
// ---------------------------------------------------------------------------
template <int MODE, int NG, int MG, int SPLITK>
__global__ __launch_bounds__(256) void gemm128_kernel(
    const bf16* __restrict__ A, const bf16* __restrict__ Bt,
    int N, int K,
    float* __restrict__ outF, bf16* __restrict__ outB,
    const float* __restrict__ bias)
{
    __shared__ __align__(16) bf16 Alds[2][128][32];
    __shared__ __align__(16) bf16 Blds[2][128][32];
    const int tid  = threadIdx.x;
    const int lane = tid & 63;
    const int w    = tid >> 6;
    const int r15  = lane & 15;
    const int quad = lane >> 4;

    const int id    = blockIdx.x + gridDim.x * (blockIdx.y + gridDim.y * blockIdx.z);
    const int xcd   = id & 7;
    const int seq   = id >> 3;
    const int nPerX = gridDim.x / NG;
    const int mPerX = gridDim.y / MG;
    const int nm    = nPerX * mPerX;
    const int z     = seq / nm;
    const int loc   = seq - z * nm;
    const int bn    = ((xcd % NG) * nPerX + (loc % nPerX)) * 128;
    const int bm    = ((xcd / NG) * mPerX + (loc / nPerX)) * 128;

    const int wm = (w >> 1) * 64;
    const int wn = (w & 1) * 64;

    floatx4 acc[4][4];
#pragma unroll
    for (int i = 0; i < 4; ++i)
#pragma unroll
        for (int j = 0; j < 4; ++j) acc[i][j] = (floatx4)(0.f);

    const int KS    = K / SPLITK;
    const int kBase = (SPLITK > 1) ? z * KS : 0;
    const int nIter = KS / 32;

    const int srow = lane >> 2;
    const int gch  = (lane & 3) ^ ((lane >> 3) & 3);
    const bf16* aptr = A + (size_t)(bm + w * 16 + srow) * K + kBase + gch * 8;
    const bf16* bptr = Bt + (size_t)(bn + w * 16 + srow) * K + kBase + gch * 8;

#pragma unroll
    for (int rr = 0; rr < 2; ++rr) {
        ld_g2l(aptr + (size_t)rr * 64 * K, &Alds[0][rr * 64 + w * 16][0]);
        ld_g2l(bptr + (size_t)rr * 64 * K, &Blds[0][rr * 64 + w * 16][0]);
    }

    const int pcs = quad ^ ((r15 >> 1) & 3);

    for (int it = 0; it < nIter; ++it) {
        const int buf = it & 1;
        __syncthreads();
        if (it + 1 < nIter) {
            const int k2 = (it + 1) * 32;
#pragma unroll
            for (int rr = 0; rr < 2; ++rr) {
                ld_g2l(aptr + (size_t)rr * 64 * K + k2, &Alds[buf ^ 1][rr * 64 + w * 16][0]);
                ld_g2l(bptr + (size_t)rr * 64 * K + k2, &Blds[buf ^ 1][rr * 64 + w * 16][0]);
            }
        }
        bf16x8 af[4], bfr[4];
#pragma unroll
        for (int i = 0; i < 4; ++i)
            af[i] = *(const bf16x8*)(&Alds[buf][wm + i * 16 + r15][pcs * 8]);
#pragma unroll
        for (int j = 0; j < 4; ++j)
            bfr[j] = *(const bf16x8*)(&Blds[buf][wn + j * 16 + r15][pcs * 8]);
#pragma unroll
        for (int i = 0; i < 4; ++i)
#pragma unroll
            for (int j = 0; j < 4; ++j)
                acc[i][j] = __builtin_amdgcn_mfma_f32_16x16x32_bf16(
                    af[i], bfr[j], acc[i][j], 0, 0, 0);
    }

    const int row0 = bm + wm + quad * 4;
    const int col0 = bn + wn + r15;
    float* po = (MODE == 3) ? outF + (size_t)z * 2048 * 1024 : outF;
#pragma unroll
    for (int i = 0; i < 4; ++i) {
#pragma unroll
        for (int reg = 0; reg < 4; ++reg) {
            const int row = row0 + i * 16 + reg;
#pragma unroll
            for (int j = 0; j < 4; ++j) {
                const int col = col0 + j * 16;
                float v = acc[i][j][reg];
                if (MODE == 0) {
                    outB[(size_t)row * N + col] = (bf16)v;
                } else if (MODE == 2) {
                    v += bias[col];
                    outB[(size_t)row * N + col] = (bf16)fmaxf(v, 0.f);
                } else {
                    po[(size_t)row * N + col] = v;
                }
            }
        }
    }
}

// ---------------------------------------------------------------------------
// 64x64 MFMA GEMM (Oproj): BK=64, dbuf, XOR swizzle, XCD swizzle.
// outF = acc + bias[col] + res[row][col]
// ---------------------------------------------------------------------------
template <int NG, int MG>
__global__ __launch_bounds__(256) void gemm64_kernel(
    const bf16* __restrict__ A, const bf16* __restrict__ Bt,
    int N, int K,
    float* __restrict__ outF, const float* __restrict__ bias,
    const float* __restrict__ res)
{
    __shared__ __align__(16) bf16 Alds[2][64][64];
    __shared__ __align__(16) bf16 Blds[2][64][64];
    const int tid  = threadIdx.x;
    const int lane = tid & 63;
    const int w    = tid >> 6;
    const int r15  = lane & 15;
    const int quad = lane >> 4;

    const int id    = blockIdx.x + gridDim.x * blockIdx.y;
    const int xcd   = id & 7;
    const int seq   = id >> 3;
    const int nPerX = gridDim.x / NG;
    const int mPerX = gridDim.y / MG;
    const int loc   = seq % (nPerX * mPerX);
    const int bn    = ((xcd % NG) * nPerX + (loc % nPerX)) * 64;
    const int bm    = ((xcd / NG) * mPerX + (loc / nPerX)) * 64;

    const int wm = (w >> 1) * 32;
    const int wn = (w & 1) * 32;

    floatx4 acc[2][2];
#pragma unroll
    for (int i = 0; i < 2; ++i)
#pragma unroll
        for (int j = 0; j < 2; ++j) acc[i][j] = (floatx4)(0.f);

    const int nIter = K / 64;
    const int lrow = lane >> 3;
    const int gch  = (lane & 7) ^ lrow;
    const bf16* aptr = A + (size_t)(bm + w * 16 + lrow) * K + gch * 8;
    const bf16* bptr = Bt + (size_t)(bn + w * 16 + lrow) * K + gch * 8;

#pragma unroll
    for (int t = 0; t < 2; ++t) {
        ld_g2l(aptr + (size_t)t * 8 * K, &Alds[0][w * 16 + t * 8][0]);
        ld_g2l(bptr + (size_t)t * 8 * K, &Blds[0][w * 16 + t * 8][0]);
    }

    for (int it = 0; it < nIter; ++it) {
        const int buf = it & 1;
        __syncthreads();
        if (it + 1 < nIter) {
            const int k2 = (it + 1) * 64;
#pragma unroll
            for (int t = 0; t < 2; ++t) {
                ld_g2l(aptr + (size_t)t * 8 * K + k2, &Alds[buf ^ 1][w * 16 + t * 8][0]);
                ld_g2l(bptr + (size_t)t * 8 * K + k2, &Blds[buf ^ 1][w * 16 + t * 8][0]);
            }
        }
#pragma unroll
        for (int kk = 0; kk < 2; ++kk) {
            const int pc = ((kk * 4 + quad) ^ (r15 & 7)) * 8;
            bf16x8 af[2], bfr[2];
#pragma unroll
            for (int i = 0; i < 2; ++i)
                af[i] = *(const bf16x8*)(&Alds[buf][wm + i * 16 + r15][pc]);
#pragma unroll
            for (int j = 0; j < 2; ++j)
                bfr[j] = *(const bf16x8*)(&Blds[buf][wn + j * 16 + r15][pc]);
#pragma unroll
            for (int i = 0; i < 2; ++i)
#pragma unroll
                for (int j = 0; j < 2; ++j)
                    acc[i][j] = __builtin_amdgcn_mfma_f32_16x16x32_bf16(
                        af[i], bfr[j], acc[i][j], 0, 0, 0);
        }
    }

    const int row0 = bm + wm + quad * 4;
    const int col0 = bn + wn + r15;
#pragma unroll
    for (int i = 0; i < 2; ++i)
#pragma unroll
        for (int reg = 0; reg < 4; ++reg) {
            const int row = row0 + i * 16 + reg;
#pragma unroll
            for (int j = 0; j < 2; ++j) {
                const int col = col0 + j * 16;
                outF[(size_t)row * N + col] =
                    acc[i][j][reg] + bias[col] + res[(size_t)row * N + col];
            }
        }
}

// ---------------------------------------------------------------------------
// Register-direct MFMA flash attention (causal), fixed-offset softmax.
// NO K/V/Q LDS staging: MFMA A/B fragments (A[m=lane&15][k=quad*8+j],
// B^T[n=lane&15][k=quad*8+j]) are 16B global loads straight from QKV / Vt.
// No __syncthreads at all — only the per-wave P C->A transform uses LDS.
// K-frags register-prefetched one step ahead (unroll 2 rotates).
// grid (16, H, 2): z=0 -> q-tile qp, z=1 -> q-tile 31-qp (balanced pair
// across blocks id and id+256 -> 2 complementary blocks/CU, 2 waves/SIMD).
// ---------------------------------------------------------------------------
__global__ __launch_bounds__(256) void attn_kernel(
    const bf16* __restrict__ qkv, const bf16* __restrict__ vt,
    bf16* __restrict__ out)
{
    __shared__ __align__(16) bf16 Ps[4][16][72];   // per-wave P tile

    const int tid  = threadIdx.x;
    const int w    = tid >> 6;
    const int lane = tid & 63;
    const int r15  = lane & 15;
    const int quad = lane >> 4;

    const int qp = blockIdx.x;
    const int h  = blockIdx.y;
    const int qt = blockIdx.z ? 31 - qp : qp;
    const int nsteps = qt + 1;
    const int q0 = qt * 64 + w * 16;               // wave's 16 q-rows

    const bf16* ksec = qkv + 1024 + h * 64;
    const bf16* vth  = vt + (size_t)h * 64 * 2048;

    // Q A-frags: lane holds Q[q0+r15][c*32 + quad*8 .. +7]
    bf16x8 qf[2];
#pragma unroll
    for (int c = 0; c < 2; ++c)
        qf[c] = *(const bf16x8*)(qkv + (size_t)(q0 + r15) * 3072 + h * 64 + c * 32 + quad * 8);

    float lacc[4] = {0.f, 0.f, 0.f, 0.f};
    floatx4 O[4];
#pragma unroll
    for (int j = 0; j < 4; ++j) O[j] = (floatx4)(0.f);

    // K B-frags for step 0: lane holds K[s0+j*16+r15][c*32 + quad*8 ..]
    bf16x8 kf[8];
#pragma unroll
    for (int j = 0; j < 4; ++j)
#pragma unroll
        for (int c = 0; c < 2; ++c)
            kf[j * 2 + c] = *(const bf16x8*)(ksec + (size_t)(j * 16 + r15) * 3072 + c * 32 + quad * 8);

#pragma unroll 2
    for (int sb = 0; sb < nsteps; ++sb) {
        const int s0 = sb * 64;
        // V B-frags for this step: lane holds Vt[j*16+r15][s0 + c*32 + quad*8]
        bf16x8 vf[8];
#pragma unroll
        for (int j = 0; j < 4; ++j)
#pragma unroll
            for (int c = 0; c < 2; ++c)
                vf[j * 2 + c] = *(const bf16x8*)(vth + (size_t)(j * 16 + r15) * 2048 + s0 + c * 32 + quad * 8);
        // prefetch next step's K-frags
        bf16x8 kn[8];
        if (sb + 1 < nsteps) {
            const int s1 = s0 + 64;
#pragma unroll
            for (int j = 0; j < 4; ++j)
#pragma unroll
                for (int c = 0; c < 2; ++c)
                    kn[j * 2 + c] = *(const bf16x8*)(ksec + (size_t)(s1 + j * 16 + r15) * 3072 + c * 32 + quad * 8);
        }

        // S = Q K^T
        floatx4 S[4];
#pragma unroll
        for (int j = 0; j < 4; ++j) S[j] = (floatx4)(0.f);
#pragma unroll
        for (int c = 0; c < 2; ++c)
#pragma unroll
            for (int j = 0; j < 4; ++j)
                S[j] = __builtin_amdgcn_mfma_f32_16x16x32_bf16(qf[c], kf[j * 2 + c], S[j], 0, 0, 0);

        // fixed-offset softmax: p = exp2(S*0.125*log2e - 28.854)
        const bool diag = (sb == qt);
        const int rowl = w * 16 + quad * 4;
#pragma unroll
        for (int j = 0; j < 4; ++j) {
            const int col = j * 16 + r15;
#pragma unroll
            for (int r = 0; r < 4; ++r) {
                float p = exp2f(fmaf(S[j][r], 0.18033688f, -28.853901f));
                if (diag && col > rowl + r) p = 0.f;
                S[j][r] = p;
                lacc[r] += p;
            }
        }
        // P: C-layout -> A-layout via per-wave LDS (no barrier)
#pragma unroll
        for (int r = 0; r < 4; ++r)
#pragma unroll
            for (int j = 0; j < 4; ++j)
                Ps[w][quad * 4 + r][j * 16 + r15] = (bf16)S[j][r];
        bf16x8 pa[2];
#pragma unroll
        for (int c = 0; c < 2; ++c)
            pa[c] = *(const bf16x8*)&Ps[w][r15][c * 32 + quad * 8];
        // O += P V
#pragma unroll
        for (int c = 0; c < 2; ++c)
#pragma unroll
            for (int j = 0; j < 4; ++j)
                O[j] = __builtin_amdgcn_mfma_f32_16x16x32_bf16(pa[c], vf[j * 2 + c], O[j], 0, 0, 0);
        // rotate prefetch
#pragma unroll
        for (int i = 0; i < 8; ++i) kf[i] = kn[i];
    }

    // reduce l across the 16-lane row group
#pragma unroll
    for (int r = 0; r < 4; ++r) {
#pragma unroll
        for (int d = 1; d < 16; d <<= 1) lacc[r] += __shfl_xor(lacc[r], d);
    }
    // epilogue
#pragma unroll
    for (int r = 0; r < 4; ++r) {
        const float inv = 1.0f / lacc[r];
        const int row = q0 + quad * 4 + r;
#pragma unroll
        for (int j = 0; j < 4; ++j)
            out[(size_t)row * 1024 + h * 64 + j * 16 + r15] = (bf16)(O[j][r] * inv);
    }
}

// ---------------------------------------------------------------------------
extern "C" void kernel_launch(void* const* d_in, const int* in_sizes, int n_in,
                              void* d_out, int out_size, void* d_ws, size_t ws_size,
                              hipStream_t stream)
{
    const float* x    = (const float*)d_in[0];
    const float* Wq   = (const float*)d_in[1];
    const float* Wk   = (const float*)d_in[2];
    const float* Wv   = (const float*)d_in[3];
    const float* Wo   = (const float*)d_in[4];
    const float* bo   = (const float*)d_in[5];
    const float* W1   = (const float*)d_in[6];
    const float* b1   = (const float*)d_in[7];
    const float* W2   = (const float*)d_in[8];
    const float* b2   = (const float*)d_in[9];
    const float* ln1s = (const float*)d_in[10];
    const float* ln1b = (const float*)d_in[11];
    const float* ln2s = (const float*)d_in[12];
    const float* ln2b = (const float*)d_in[13];

    char* ws = (char*)d_ws;
    bf16*  Wqkvt = (bf16*)(ws + 0);          //  6 MB [3072][1024]
    bf16*  Wot   = (bf16*)(ws + 6291456);    //  2 MB [1024][1024]
    bf16*  W1t   = (bf16*)(ws + 8388608);    //  8 MB [4096][1024]
    bf16*  W2t   = (bf16*)(ws + 16777216);   //  8 MB [1024][4096]
    bf16*  hbuf  = (bf16*)(ws + 25165824);   //  4 MB [2048][1024]
    bf16*  QKV   = (bf16*)(ws + 29360128);   // 12 MB [2048][3072]
    bf16*  Vt    = (bf16*)(ws + 41943040);   //  4 MB [16][64][2048]
    bf16*  Obuf  = (bf16*)(ws + 46137344);   //  4 MB [2048][1024]
    float* x1    = (float*)(ws + 50331648);  //  8 MB [2048][1024]
    bf16*  h2    = (bf16*)(ws + 58720256);   //  4 MB [2048][1024]
    bf16*  ff1   = (bf16*)(ws + 62914560);   // 16 MB [2048][4096]
    float* psum  = (float*)(ws + 79691776);  // 32 MB [4][2048][1024]

    const dim3 tb(32, 8);
    transpose_cast_qkv_kernel<<<dim3(2, 32, 48), tb, 0, stream>>>(Wq, Wk, Wv, Wqkvt);
    transpose_cast_kernel<<<dim3(32, 32, 1), tb, 0, stream>>>(Wo, Wot, 1024, 1024, 0, 0);
    transpose_cast_kernel<<<dim3(128, 32, 1), tb, 0, stream>>>(W1, W1t, 1024, 4096, 0, 0);
    transpose_cast_kernel<<<dim3(32, 128, 1), tb, 0, stream>>>(W2, W2t, 4096, 1024, 0, 0);

    ln_kernel<<<2048, 256, 0, stream>>>(x, ln1s, ln1b, hbuf);
    gemm128_kernel<0,4,2,1><<<dim3(24, 16), 256, 0, stream>>>(hbuf, Wqkvt, 3072, 1024, nullptr, QKV, nullptr);
    transpose_head_kernel<<<dim3(2, 64, 16), tb, 0, stream>>>(QKV, Vt, 2048);
    attn_kernel<<<dim3(16, 16, 2), 256, 0, stream>>>(QKV, Vt, Obuf);
    gemm64_kernel<4,2><<<dim3(16, 32), 256, 0, stream>>>(Obuf, Wot, 1024, 1024, x1, bo, x);
    ln_kernel<<<2048, 256, 0, stream>>>(x1, ln2s, ln2b, h2);
    gemm128_kernel<2,4,2,1><<<dim3(32, 16), 256, 0, stream>>>(h2, W1t, 4096, 1024, nullptr, ff1, b1);
    gemm128_kernel<3,2,4,4><<<dim3(8, 16, 4), 256, 0, stream>>>(ff1, W2t, 1024, 4096, psum, nullptr, nullptr);
    reduce4_kernel<<<2048, 256, 0, stream>>>(psum, b2, x1, (float*)d_out);
}

// Round 9
// 275.270 us; speedup vs baseline: 1.0952x; 1.0952x over previous
//
#include <hip/hip_runtime.h>
#include <cstdint>

// T=2048, D=1024, H=16, HS=64, DFF=4096. fp32 in/out, bf16 MFMA internally.

typedef __bf16 bf16;
typedef __bf16 bf16x4 __attribute__((ext_vector_type(4)));
typedef __bf16 bf16x8 __attribute__((ext_vector_type(8)));
typedef float floatx4 __attribute__((ext_vector_type(4)));

// async global->LDS 16B/lane. LDS dest is wave-uniform base + lane*16 (HW rule).
__device__ __forceinline__ void ld_g2l(const bf16* g, bf16* l) {
    __builtin_amdgcn_global_load_lds(
        (const __attribute__((address_space(1))) void*)g,
        (__attribute__((address_space(3))) void*)l, 16, 0, 0);
}

// ---------------------------------------------------------------------------
// Tiled transpose + fp32->bf16 cast:  dst[c][r] = (bf16)src[r][c], batched.
// ---------------------------------------------------------------------------
__global__ __launch_bounds__(256) void transpose_cast_kernel(
    const float* __restrict__ src, bf16* __restrict__ dst,
    int R, int C, long long sBatch, long long dBatch)
{
    __shared__ float tile[32][33];
    const int tx = threadIdx.x, ty = threadIdx.y;
    src += (size_t)blockIdx.z * sBatch;
    dst += (size_t)blockIdx.z * dBatch;
    const int c0 = blockIdx.x * 32, r0 = blockIdx.y * 32;
#pragma unroll
    for (int i = ty; i < 32; i += 8)
        tile[i][tx] = src[(size_t)(r0 + i) * C + c0 + tx];
    __syncthreads();
#pragma unroll
    for (int i = ty; i < 32; i += 8)
        dst[(size_t)(c0 + i) * R + r0 + tx] = (bf16)tile[tx][i];
}

// QKV weight transpose (3 sources in one launch): grid (2, 32, 48)
__global__ __launch_bounds__(256) void transpose_cast_qkv_kernel(
    const float* __restrict__ Wq, const float* __restrict__ Wk,
    const float* __restrict__ Wv, bf16* __restrict__ dst)
{
    __shared__ float tile[32][33];
    const int tx = threadIdx.x, ty = threadIdx.y;
    const int m = blockIdx.z >> 4, h = blockIdx.z & 15;
    const float* src = (m == 0 ? Wq : (m == 1 ? Wk : Wv)) + h * 65536;
    bf16* d = dst + m * 1048576 + h * 65536;
    const int c0 = blockIdx.x * 32, r0 = blockIdx.y * 32;
#pragma unroll
    for (int i = ty; i < 32; i += 8)
        tile[i][tx] = src[(size_t)(r0 + i) * 64 + c0 + tx];
    __syncthreads();
#pragma unroll
    for (int i = ty; i < 32; i += 8)
        d[(size_t)(c0 + i) * 1024 + r0 + tx] = (bf16)tile[tx][i];
}

// ---------------------------------------------------------------------------
// Head-transpose from QKV: dst[h][j][s] = qkv[s][colOff + h*64 + j]   (bf16)
// ---------------------------------------------------------------------------
__global__ __launch_bounds__(256) void transpose_head_kernel(
    const bf16* __restrict__ qkv, bf16* __restrict__ dst, int colOff)
{
    __shared__ bf16 tile[32][33];
    const int tx = threadIdx.x, ty = threadIdx.y;
    const int h = blockIdx.z;
    const int j0 = blockIdx.x * 32, s0 = blockIdx.y * 32;
#pragma unroll
    for (int i = ty; i < 32; i += 8)
        tile[i][tx] = qkv[(size_t)(s0 + i) * 3072 + colOff + h * 64 + j0 + tx];
    __syncthreads();
#pragma unroll
    for (int i = ty; i < 32; i += 8)
        dst[(size_t)h * 64 * 2048 + (size_t)(j0 + i) * 2048 + s0 + tx] = tile[tx][i];
}

// ---------------------------------------------------------------------------
// Row LayerNorm over D=1024: fp32 in -> bf16 out. One block (256 thr) per row.
// ---------------------------------------------------------------------------
__global__ __launch_bounds__(256) void ln_kernel(
    const float* __restrict__ x, const float* __restrict__ sc,
    const float* __restrict__ bi, bf16* __restrict__ out)
{
    const int row = blockIdx.x;
    const int tid = threadIdx.x;
    const float4 v = ((const float4*)(x + (size_t)row * 1024))[tid];
    float s1 = v.x + v.y + v.z + v.w;
    float s2 = v.x * v.x + v.y * v.y + v.z * v.z + v.w * v.w;
#pragma unroll
    for (int mm = 1; mm < 64; mm <<= 1) {
        s1 += __shfl_xor(s1, mm);
        s2 += __shfl_xor(s2, mm);
    }
    __shared__ float w1[4], w2[4];
    const int wave = tid >> 6, lane = tid & 63;
    if (lane == 0) { w1[wave] = s1; w2[wave] = s2; }
    __syncthreads();
    s1 = w1[0] + w1[1] + w1[2] + w1[3];
    s2 = w2[0] + w2[1] + w2[2] + w2[3];
    const float mu = s1 * (1.f / 1024.f);
    const float var = fmaxf(s2 * (1.f / 1024.f) - mu * mu, 0.f);
    const float rr = rsqrtf(var + 1e-6f);
    const float4 scv = ((const float4*)sc)[tid];
    const float4 biv = ((const float4*)bi)[tid];
    bf16x4 ov;
    ov[0] = (bf16)((v.x - mu) * rr * scv.x + biv.x);
    ov[1] = (bf16)((v.y - mu) * rr * scv.y + biv.y);
    ov[2] = (bf16)((v.z - mu) * rr * scv.z + biv.z);
    ov[3] = (bf16)((v.w - mu) * rr * scv.w + biv.w);
    *(bf16x4*)(out + (size_t)row * 1024 + tid * 4) = ov;
}

// ---------------------------------------------------------------------------
// Split-K reduce (4 partials):  out = p0+p1+p2+p3 + bias[col] + res
// ---------------------------------------------------------------------------
__global__ __launch_bounds__(256) void reduce4_kernel(
    const float* __restrict__ p, const float* __restrict__ bias,
    const float* __restrict__ res, float* __restrict__ out)
{
    const int idx = blockIdx.x * 256 + threadIdx.x;
    const int c4 = idx & 255;
    const float4 a0 = ((const float4*)p)[idx];
    const float4 a1 = ((const float4*)(p + 2097152))[idx];
    const float4 a2 = ((const float4*)(p + 4194304))[idx];
    const float4 a3 = ((const float4*)(p + 6291456))[idx];
    const float4 bi = ((const float4*)bias)[c4];
    const float4 r = ((const float4*)res)[idx];
    float4 o;
    o.x = (a0.x + a1.x) + (a2.x + a3.x) + bi.x + r.x;
    o.y = (a0.y + a1.y) + (a2.y + a3.y) + bi.y + r.y;
    o.z = (a0.z + a1.z) + (a2.z + a3.z) + bi.z + r.z;
    o.w = (a0.w + a1.w) + (a2.w + a3.w) + bi.w + r.w;
    ((float4*)out)[idx] = o;
}

// ---------------------------------------------------------------------------
// 128x128 MFMA GEMM (m97-class): BK=32, dbuf global_load_lds, bank swizzle,
// XCD swizzle <NG,MG>.
// MODE 0: outB=(bf16)acc | 2: outB=relu(acc+bias) | 3: psum[z*M*N+..]=acc
// ---------------------------------------------------------------------------
template <int MODE, int NG, int MG, int SPLITK>
__global__ __launch_bounds__(256) void gemm128_kernel(
    const bf16* __restrict__ A, const bf16* __restrict__ Bt,
    int N, int K,
    float* __restrict__ outF, bf16* __restrict__ outB,
    const float* __restrict__ bias)
{
    __shared__ __align__(16) bf16 Alds[2][128][32];
    __shared__ __align__(16) bf16 Blds[2][128][32];
    const int tid  = threadIdx.x;
    const int lane = tid & 63;
    const int w    = tid >> 6;
    const int r15  = lane & 15;
    const int quad = lane >> 4;

    const int id    = blockIdx.x + gridDim.x * (blockIdx.y + gridDim.y * blockIdx.z);
    const int xcd   = id & 7;
    const int seq   = id >> 3;
    const int nPerX = gridDim.x / NG;
    const int mPerX = gridDim.y / MG;
    const int nm    = nPerX * mPerX;
    const int z     = seq / nm;
    const int loc   = seq - z * nm;
    const int bn    = ((xcd % NG) * nPerX + (loc % nPerX)) * 128;
    const int bm    = ((xcd / NG) * mPerX + (loc / nPerX)) * 128;

    const int wm = (w >> 1) * 64;
    const int wn = (w & 1) * 64;

    floatx4 acc[4][4];
#pragma unroll
    for (int i = 0; i < 4; ++i)
#pragma unroll
        for (int j = 0; j < 4; ++j) acc[i][j] = (floatx4)(0.f);

    const int KS    = K / SPLITK;
    const int kBase = (SPLITK > 1) ? z * KS : 0;
    const int nIter = KS / 32;

    const int srow = lane >> 2;
    const int gch  = (lane & 3) ^ ((lane >> 3) & 3);
    const bf16* aptr = A + (size_t)(bm + w * 16 + srow) * K + kBase + gch * 8;
    const bf16* bptr = Bt + (size_t)(bn + w * 16 + srow) * K + kBase + gch * 8;

#pragma unroll
    for (int rr = 0; rr < 2; ++rr) {
        ld_g2l(aptr + (size_t)rr * 64 * K, &Alds[0][rr * 64 + w * 16][0]);
        ld_g2l(bptr + (size_t)rr * 64 * K, &Blds[0][rr * 64 + w * 16][0]);
    }

    const int pcs = quad ^ ((r15 >> 1) & 3);

    for (int it = 0; it < nIter; ++it) {
        const int buf = it & 1;
        __syncthreads();
        if (it + 1 < nIter) {
            const int k2 = (it + 1) * 32;
#pragma unroll
            for (int rr = 0; rr < 2; ++rr) {
                ld_g2l(aptr + (size_t)rr * 64 * K + k2, &Alds[buf ^ 1][rr * 64 + w * 16][0]);
                ld_g2l(bptr + (size_t)rr * 64 * K + k2, &Blds[buf ^ 1][rr * 64 + w * 16][0]);
            }
        }
        bf16x8 af[4], bfr[4];
#pragma unroll
        for (int i = 0; i < 4; ++i)
            af[i] = *(const bf16x8*)(&Alds[buf][wm + i * 16 + r15][pcs * 8]);
#pragma unroll
        for (int j = 0; j < 4; ++j)
            bfr[j] = *(const bf16x8*)(&Blds[buf][wn + j * 16 + r15][pcs * 8]);
#pragma unroll
        for (int i = 0; i < 4; ++i)
#pragma unroll
            for (int j = 0; j < 4; ++j)
                acc[i][j] = __builtin_amdgcn_mfma_f32_16x16x32_bf16(
                    af[i], bfr[j], acc[i][j], 0, 0, 0);
    }

    const int row0 = bm + wm + quad * 4;
    const int col0 = bn + wn + r15;
    float* po = (MODE == 3) ? outF + (size_t)z * 2048 * 1024 : outF;
#pragma unroll
    for (int i = 0; i < 4; ++i) {
#pragma unroll
        for (int reg = 0; reg < 4; ++reg) {
            const int row = row0 + i * 16 + reg;
#pragma unroll
            for (int j = 0; j < 4; ++j) {
                const int col = col0 + j * 16;
                float v = acc[i][j][reg];
                if (MODE == 0) {
                    outB[(size_t)row * N + col] = (bf16)v;
                } else if (MODE == 2) {
                    v += bias[col];
                    outB[(size_t)row * N + col] = (bf16)fmaxf(v, 0.f);
                } else {
                    po[(size_t)row * N + col] = v;
                }
            }
        }
    }
}

// ---------------------------------------------------------------------------
// 64x64 MFMA GEMM (Oproj): BK=64, dbuf, XOR swizzle, XCD swizzle.
// outF = acc + bias[col] + res[row][col]
// ---------------------------------------------------------------------------
template <int NG, int MG>
__global__ __launch_bounds__(256) void gemm64_kernel(
    const bf16* __restrict__ A, const bf16* __restrict__ Bt,
    int N, int K,
    float* __restrict__ outF, const float* __restrict__ bias,
    const float* __restrict__ res)
{
    __shared__ __align__(16) bf16 Alds[2][64][64];
    __shared__ __align__(16) bf16 Blds[2][64][64];
    const int tid  = threadIdx.x;
    const int lane = tid & 63;
    const int w    = tid >> 6;
    const int r15  = lane & 15;
    const int quad = lane >> 4;

    const int id    = blockIdx.x + gridDim.x * blockIdx.y;
    const int xcd   = id & 7;
    const int seq   = id >> 3;
    const int nPerX = gridDim.x / NG;
    const int mPerX = gridDim.y / MG;
    const int loc   = seq % (nPerX * mPerX);
    const int bn    = ((xcd % NG) * nPerX + (loc % nPerX)) * 64;
    const int bm    = ((xcd / NG) * mPerX + (loc / nPerX)) * 64;

    const int wm = (w >> 1) * 32;
    const int wn = (w & 1) * 32;

    floatx4 acc[2][2];
#pragma unroll
    for (int i = 0; i < 2; ++i)
#pragma unroll
        for (int j = 0; j < 2; ++j) acc[i][j] = (floatx4)(0.f);

    const int nIter = K / 64;
    const int lrow = lane >> 3;
    const int gch  = (lane & 7) ^ lrow;
    const bf16* aptr = A + (size_t)(bm + w * 16 + lrow) * K + gch * 8;
    const bf16* bptr = Bt + (size_t)(bn + w * 16 + lrow) * K + gch * 8;

#pragma unroll
    for (int t = 0; t < 2; ++t) {
        ld_g2l(aptr + (size_t)t * 8 * K, &Alds[0][w * 16 + t * 8][0]);
        ld_g2l(bptr + (size_t)t * 8 * K, &Blds[0][w * 16 + t * 8][0]);
    }

    for (int it = 0; it < nIter; ++it) {
        const int buf = it & 1;
        __syncthreads();
        if (it + 1 < nIter) {
            const int k2 = (it + 1) * 64;
#pragma unroll
            for (int t = 0; t < 2; ++t) {
                ld_g2l(aptr + (size_t)t * 8 * K + k2, &Alds[buf ^ 1][w * 16 + t * 8][0]);
                ld_g2l(bptr + (size_t)t * 8 * K + k2, &Blds[buf ^ 1][w * 16 + t * 8][0]);
            }
        }
#pragma unroll
        for (int kk = 0; kk < 2; ++kk) {
            const int pc = ((kk * 4 + quad) ^ (r15 & 7)) * 8;
            bf16x8 af[2], bfr[2];
#pragma unroll
            for (int i = 0; i < 2; ++i)
                af[i] = *(const bf16x8*)(&Alds[buf][wm + i * 16 + r15][pc]);
#pragma unroll
            for (int j = 0; j < 2; ++j)
                bfr[j] = *(const bf16x8*)(&Blds[buf][wn + j * 16 + r15][pc]);
#pragma unroll
            for (int i = 0; i < 2; ++i)
#pragma unroll
                for (int j = 0; j < 2; ++j)
                    acc[i][j] = __builtin_amdgcn_mfma_f32_16x16x32_bf16(
                        af[i], bfr[j], acc[i][j], 0, 0, 0);
        }
    }

    const int row0 = bm + wm + quad * 4;
    const int col0 = bn + wn + r15;
#pragma unroll
    for (int i = 0; i < 2; ++i)
#pragma unroll
        for (int reg = 0; reg < 4; ++reg) {
            const int row = row0 + i * 16 + reg;
#pragma unroll
            for (int j = 0; j < 2; ++j) {
                const int col = col0 + j * 16;
                outF[(size_t)row * N + col] =
                    acc[i][j][reg] + bias[col] + res[(size_t)row * N + col];
            }
        }
}

// ---------------------------------------------------------------------------
// MFMA flash attention (causal), fixed-offset softmax, LDS-staged (R7 body).
// grid (16,16,2) = 512 blocks -> 2 blocks/CU; blocks id and id+256 hold the
// complementary q-tiles qp / 31-qp (33 steps per CU, balanced). XCD
// head-grouping: 2 heads per XCD -> K/V (1 MB) L2-resident.
// ---------------------------------------------------------------------------
__global__ __launch_bounds__(256) void attn_kernel(
    const bf16* __restrict__ qkv, const bf16* __restrict__ vt,
    bf16* __restrict__ out)
{
    __shared__ __align__(16) bf16 Qs[64][64];
    __shared__ __align__(16) bf16 Ks[2][64][64];
    __shared__ __align__(16) bf16 Vs[2][64][64];
    __shared__ __align__(16) bf16 Ps[4][16][72];

    const int tid  = threadIdx.x;
    const int w    = tid >> 6;
    const int lane = tid & 63;
    const int r15  = lane & 15;
    const int quad = lane >> 4;
    const int rl   = lane >> 3;                   // 0..7 row in 8-row group
    const int gsw  = (lane & 7) ^ (rl & 7);       // swizzled global chunk

    // XCD head-grouping: id' in [0,256); xcd = id'&7 -> heads {2x, 2x+1}
    const int idp = blockIdx.x + 16 * blockIdx.y;
    const int seq = idp >> 3;
    const int h   = (idp & 7) * 2 + (seq & 1);
    const int qp  = seq >> 1;                     // 0..15
    const int qt  = blockIdx.z ? 31 - qp : qp;
    const int qrow0 = qt * 64;

    const bf16* qsec = qkv + h * 64;
    const bf16* ksec = qkv + 1024 + h * 64;
    const bf16* vth  = vt + (size_t)h * 64 * 2048;

    // stage Q (swizzled, g2l) + prefetch K/V step 0 into buf 0
#pragma unroll
    for (int t = 0; t < 2; ++t) {
        const int r = t * 32 + w * 8 + rl;
        ld_g2l(qsec + (size_t)(qrow0 + r) * 3072 + gsw * 8, &Qs[t * 32 + w * 8][0]);
        ld_g2l(ksec + (size_t)r * 3072 + gsw * 8, &Ks[0][t * 32 + w * 8][0]);
        ld_g2l(vth + (size_t)r * 2048 + gsw * 8, &Vs[0][t * 32 + w * 8][0]);
    }
    __syncthreads();   // all staging landed

    bf16x8 qf[2];
#pragma unroll
    for (int c = 0; c < 2; ++c) {
        const int p = ((c * 4 + quad) ^ (r15 & 7)) * 8;
        qf[c] = *(const bf16x8*)&Qs[w * 16 + r15][p];
    }

    float lacc[4] = {0.f, 0.f, 0.f, 0.f};
    floatx4 O[4];
#pragma unroll
    for (int j = 0; j < 4; ++j) O[j] = (floatx4)(0.f);

#pragma unroll 1
    for (int sb = 0; sb <= qt; ++sb) {
        const int buf = sb & 1;
        if (sb < qt) {   // prefetch next K/V into buf^1
            const int s1 = (sb + 1) * 64;
#pragma unroll
            for (int t = 0; t < 2; ++t) {
                const int r = t * 32 + w * 8 + rl;
                ld_g2l(ksec + (size_t)(s1 + r) * 3072 + gsw * 8, &Ks[buf ^ 1][t * 32 + w * 8][0]);
                ld_g2l(vth + (size_t)r * 2048 + s1 + gsw * 8, &Vs[buf ^ 1][t * 32 + w * 8][0]);
            }
        }

        // S = Q K^T  (wave's 16 rows x 64 keys)
        floatx4 S[4];
#pragma unroll
        for (int j = 0; j < 4; ++j) S[j] = (floatx4)(0.f);
#pragma unroll
        for (int c = 0; c < 2; ++c) {
#pragma unroll
            for (int j = 0; j < 4; ++j) {
                const int p = ((c * 4 + quad) ^ (r15 & 7)) * 8;
                const bf16x8 b = *(const bf16x8*)&Ks[buf][j * 16 + r15][p];
                S[j] = __builtin_amdgcn_mfma_f32_16x16x32_bf16(qf[c], b, S[j], 0, 0, 0);
            }
        }
        // fixed-offset softmax: p = exp2(S*0.125*log2e - 28.854)
        const bool diag = (sb == qt);
        const int rowl = w * 16 + quad * 4;
#pragma unroll
        for (int j = 0; j < 4; ++j) {
            const int col = j * 16 + r15;
#pragma unroll
            for (int r = 0; r < 4; ++r) {
                float p = exp2f(fmaf(S[j][r], 0.18033688f, -28.853901f));
                if (diag && col > rowl + r) p = 0.f;
                S[j][r] = p;
                lacc[r] += p;
            }
        }
        // P: C-layout -> A-layout via per-wave LDS (no barrier)
#pragma unroll
        for (int r = 0; r < 4; ++r)
#pragma unroll
            for (int j = 0; j < 4; ++j)
                Ps[w][quad * 4 + r][j * 16 + r15] = (bf16)S[j][r];
        // O += P V
#pragma unroll
        for (int c = 0; c < 2; ++c) {
            const bf16x8 a = *(const bf16x8*)&Ps[w][r15][c * 32 + quad * 8];
#pragma unroll
            for (int j = 0; j < 4; ++j) {
                const int p = ((c * 4 + quad) ^ (r15 & 7)) * 8;
                const bf16x8 b = *(const bf16x8*)&Vs[buf][j * 16 + r15][p];
                O[j] = __builtin_amdgcn_mfma_f32_16x16x32_bf16(a, b, O[j], 0, 0, 0);
            }
        }
        __syncthreads();  // drain prefetch (vmcnt) + protect buf reuse
    }
    // reduce l across the 16-lane row group (once per tile)
#pragma unroll
    for (int r = 0; r < 4; ++r) {
#pragma unroll
        for (int d = 1; d < 16; d <<= 1) lacc[r] += __shfl_xor(lacc[r], d);
    }
    // epilogue: out[q][h*64+dim] = O / l
#pragma unroll
    for (int r = 0; r < 4; ++r) {
        const float inv = 1.0f / lacc[r];
        const int row = qrow0 + w * 16 + quad * 4 + r;
#pragma unroll
        for (int j = 0; j < 4; ++j)
            out[(size_t)row * 1024 + h * 64 + j * 16 + r15] = (bf16)(O[j][r] * inv);
    }
}

// ---------------------------------------------------------------------------
extern "C" void kernel_launch(void* const* d_in, const int* in_sizes, int n_in,
                              void* d_out, int out_size, void* d_ws, size_t ws_size,
                              hipStream_t stream)
{
    const float* x    = (const float*)d_in[0];
    const float* Wq   = (const float*)d_in[1];
    const float* Wk   = (const float*)d_in[2];
    const float* Wv   = (const float*)d_in[3];
    const float* Wo   = (const float*)d_in[4];
    const float* bo   = (const float*)d_in[5];
    const float* W1   = (const float*)d_in[6];
    const float* b1   = (const float*)d_in[7];
    const float* W2   = (const float*)d_in[8];
    const float* b2   = (const float*)d_in[9];
    const float* ln1s = (const float*)d_in[10];
    const float* ln1b = (const float*)d_in[11];
    const float* ln2s = (const float*)d_in[12];
    const float* ln2b = (const float*)d_in[13];

    char* ws = (char*)d_ws;
    bf16*  Wqkvt = (bf16*)(ws + 0);          //  6 MB [3072][1024]
    bf16*  Wot   = (bf16*)(ws + 6291456);    //  2 MB [1024][1024]
    bf16*  W1t   = (bf16*)(ws + 8388608);    //  8 MB [4096][1024]
    bf16*  W2t   = (bf16*)(ws + 16777216);   //  8 MB [1024][4096]
    bf16*  hbuf  = (bf16*)(ws + 25165824);   //  4 MB [2048][1024]
    bf16*  QKV   = (bf16*)(ws + 29360128);   // 12 MB [2048][3072]
    bf16*  Vt    = (bf16*)(ws + 41943040);   //  4 MB [16][64][2048]
    bf16*  Obuf  = (bf16*)(ws + 46137344);   //  4 MB [2048][1024]
    float* x1    = (float*)(ws + 50331648);  //  8 MB [2048][1024]
    bf16*  h2    = (bf16*)(ws + 58720256);   //  4 MB [2048][1024]
    bf16*  ff1   = (bf16*)(ws + 62914560);   // 16 MB [2048][4096]
    float* psum  = (float*)(ws + 79691776);  // 32 MB [4][2048][1024]

    const dim3 tb(32, 8);
    transpose_cast_qkv_kernel<<<dim3(2, 32, 48), tb, 0, stream>>>(Wq, Wk, Wv, Wqkvt);
    transpose_cast_kernel<<<dim3(32, 32, 1), tb, 0, stream>>>(Wo, Wot, 1024, 1024, 0, 0);
    transpose_cast_kernel<<<dim3(128, 32, 1), tb, 0, stream>>>(W1, W1t, 1024, 4096, 0, 0);
    transpose_cast_kernel<<<dim3(32, 128, 1), tb, 0, stream>>>(W2, W2t, 4096, 1024, 0, 0);

    ln_kernel<<<2048, 256, 0, stream>>>(x, ln1s, ln1b, hbuf);
    gemm128_kernel<0,4,2,1><<<dim3(24, 16), 256, 0, stream>>>(hbuf, Wqkvt, 3072, 1024, nullptr, QKV, nullptr);
    transpose_head_kernel<<<dim3(2, 64, 16), tb, 0, stream>>>(QKV, Vt, 2048);
    attn_kernel<<<dim3(16, 16, 2), 256, 0, stream>>>(QKV, Vt, Obuf);
    gemm64_kernel<4,2><<<dim3(16, 32), 256, 0, stream>>>(Obuf, Wot, 1024, 1024, x1, bo, x);
    ln_kernel<<<2048, 256, 0, stream>>>(x1, ln2s, ln2b, h2);
    gemm128_kernel<2,4,2,1><<<dim3(32, 16), 256, 0, stream>>>(h2, W1t, 4096, 1024, nullptr, ff1, b1);
    gemm128_kernel<3,2,4,4><<<dim3(8, 16, 4), 256, 0, stream>>>(ff1, W2t, 1024, 4096, psum, nullptr, nullptr);
    reduce4_kernel<<<2048, 256, 0, stream>>>(psum, b2, x1, (float*)d_out);
}